// Round 13
// baseline (415.267 us; speedup 1.0000x reference)
//
#include <hip/hip_runtime.h>
#include <hip/hip_bf16.h>

// ---------------------------------------------------------------------------
// GATv2 model pipeline. N=50000, E=400000, HID=64, H=8.
// Round 13: degree-sort reverted (measured: k_gat -2us but +11us overhead —
// imbalance was not the limiter). k_comb2 folded into k_xlxr2's A-staging
// (BN+relu inline from st_msg). 13 dispatches.
// ---------------------------------------------------------------------------

#define CDIV(a, b) (((a) + (b) - 1) / (b))

using f32x4 = __attribute__((ext_vector_type(4))) float;
using s16x8 = __attribute__((ext_vector_type(8))) short;
using u32x4 = __attribute__((ext_vector_type(4))) unsigned;

__device__ inline unsigned short f2bf(float f) {
    union { float f; unsigned u; } v; v.f = f;
    unsigned r = v.u + 0x7fff + ((v.u >> 16) & 1);   // round-nearest-even
    return (unsigned short)(r >> 16);
}
__device__ inline float bf_lo(unsigned w) {
    union { unsigned u; float f; } v; v.u = w << 16; return v.f;
}
__device__ inline float bf_hi(unsigned w) {
    union { unsigned u; float f; } v; v.u = w & 0xffff0000u; return v.f;
}
__device__ inline void unp8(u32x4 u, float* v) {
    v[0] = bf_lo(u.x); v[1] = bf_hi(u.x); v[2] = bf_lo(u.y); v[3] = bf_hi(u.y);
    v[4] = bf_lo(u.z); v[5] = bf_hi(u.z); v[6] = bf_lo(u.w); v[7] = bf_hi(u.w);
}

// Merged: blocks [0,512) -> Wt; [512,640) -> Wp1t; 640 -> Wzt+bc;
// blocks >= 641 -> in-degree count (1 atomic per edge, 50000 targets).
__global__ void k_prepcnt(const float* __restrict__ Wl, const float* __restrict__ Wr,
                          const float* __restrict__ Wp1, const float* __restrict__ Wap,
                          const float* __restrict__ Wmsg, const float* __restrict__ bap,
                          const float* __restrict__ bmsg, unsigned short* __restrict__ Wt,
                          unsigned short* __restrict__ Wp1t, unsigned short* __restrict__ Wzt,
                          float* __restrict__ bc, const int* __restrict__ ei,
                          int* __restrict__ cntI, int E) {
    int b = blockIdx.x, t = threadIdx.x;
    if (b < 512) {                       // Wt[c][k], [1024][128]
        int idx = b * 256 + t;
        int c = idx >> 7, k = idx & 127;
        float v = (c < 512) ? Wl[(size_t)k * 512 + c] : Wr[(size_t)k * 512 + (c - 512)];
        Wt[idx] = f2bf(v);
    } else if (b < 640) {                // Wp1t[c][k], [64][512]
        int idx = (b - 512) * 256 + t;
        int c = idx >> 9, k = idx & 511;
        Wp1t[idx] = f2bf(Wp1[(size_t)k * 64 + c]);
    } else if (b == 640) {               // Wzt + bc (single block)
        for (int e = t; e < 4096; e += 256) {
            int i = e >> 6, c = e & 63;
            float s = 0.f;
            for (int j = 0; j < 64; ++j) s += Wap[i * 64 + j] * Wmsg[j * 64 + c];
            Wzt[c * 128 + i] = f2bf(s);
        }
        for (int e = t; e < 4096; e += 256) {
            int k = e >> 6, c = e & 63;
            Wzt[c * 128 + 64 + k] = f2bf(Wmsg[k * 64 + c]);
        }
        if (t < 64) {
            float s = bmsg[t];
            for (int j = 0; j < 64; ++j) s += bap[j] * Wmsg[j * 64 + t];
            bc[t] = s;
        }
    } else {                             // degree count
        int e = (b - 641) * 256 + t;
        if (e < E) atomicAdd(&cntI[ei[E + e]], 1);
    }
}

// ---- parallel exclusive scan of cntI -> rowptr (3 kernels) ----
__global__ void k_bsum(const int* __restrict__ cntI, int* __restrict__ bsum, int N) {
    int b = blockIdx.x, t = threadIdx.x;
    int base = b * 1024 + t * 4;
    int s = 0;
#pragma unroll
    for (int j = 0; j < 4; ++j) { int i = base + j; if (i < N) s += cntI[i]; }
    for (int off = 32; off; off >>= 1) s += __shfl_xor(s, off, 64);
    __shared__ int wsum[4];
    if ((t & 63) == 0) wsum[t >> 6] = s;
    __syncthreads();
    if (t == 0) bsum[b] = wsum[0] + wsum[1] + wsum[2] + wsum[3];
}
__global__ void k_boff(const int* __restrict__ bsum, int* __restrict__ boff, int nb) {
    int t = threadIdx.x;
    if (t < nb) { int s = 0; for (int j = 0; j < t; ++j) s += bsum[j]; boff[t] = s; }
}
__global__ void k_scan2(const int* __restrict__ cntI, const int* __restrict__ boff,
                        int* __restrict__ rowptr, int N) {
    int b = blockIdx.x, t = threadIdx.x;
    int base = b * 1024 + t * 4;
    int v[4]; int s = 0;
#pragma unroll
    for (int j = 0; j < 4; ++j) { int i = base + j; v[j] = (i < N) ? cntI[i] : 0; s += v[j]; }
    __shared__ int ls[256];
    ls[t] = s; __syncthreads();
    for (int off = 1; off < 256; off <<= 1) {
        int tv = (t >= (int)off) ? ls[t - off] : 0;
        __syncthreads(); ls[t] += tv; __syncthreads();
    }
    int run = ls[t] - s + boff[b];
#pragma unroll
    for (int j = 0; j < 4; ++j) { run += v[j]; int i = base + j; if (i < N) rowptr[i + 1] = run; }
    if (b == 0 && t == 0) rowptr[0] = 0;
}

// Scatter edges into CSR order: store source node AND edge id.
__global__ void k_fill(const int* __restrict__ ei, const int* __restrict__ rowptr,
                       int* __restrict__ cursor, int* __restrict__ esrc,
                       int* __restrict__ eidx, int E) {
    int e = blockIdx.x * blockDim.x + threadIdx.x;
    if (e >= E) return;
    int dst = ei[E + e];
    int pos = rowptr[dst] + atomicAdd(&cursor[dst], 1);
    esrc[pos] = ei[e];
    eidx[pos] = e;
}

// One wave per node: agg = deg>0 ? mean_{in-edges}(edge_attr)@W_ep + b_ep : 0
// (gathered via CSR, 4 edges x 16 ch per iteration, no atomics), then
// combin row = [bf16(x) | bf16(agg)] with wave-uniform shuffles.
__global__ void k_combin(const float* __restrict__ x, const float* __restrict__ ea,
                         const int* __restrict__ rowptr, const int* __restrict__ eidx,
                         const float* __restrict__ Wep, const float* __restrict__ bep,
                         unsigned* __restrict__ combin32, int N) {
    int wid = (blockIdx.x * blockDim.x + threadIdx.x) >> 6;
    int lane = threadIdx.x & 63;
    if (wid >= N) return;
    int e0 = rowptr[wid], e1 = rowptr[wid + 1];
    int deg = e1 - e0;
    int le = lane >> 4, ch = lane & 15;
    float part = 0.f;
    for (int p = e0 + le; p < e1; p += 4)
        part += ea[(size_t)eidx[p] * 16 + ch];
    part += __shfl_xor(part, 16, 64);
    part += __shfl_xor(part, 32, 64);          // full sum for channel ch
    float mval = (deg > 0) ? part / (float)deg : 0.f;
    float aggv = bep[lane];
#pragma unroll
    for (int j = 0; j < 16; ++j) {
        float mj = __shfl(mval, j, 64);        // lane j holds channel j
        aggv = fmaf(mj, Wep[j * 64 + lane], aggv);
    }
    if (deg == 0) aggv = 0.f;
    float xv = x[(size_t)wid * 64 + lane];
    int i0 = (lane & 31) * 2;                  // uniform shuffles, select after
    float ax = __shfl(xv, i0, 64);
    float bx = __shfl(xv, i0 + 1, 64);
    float aa = __shfl(aggv, i0, 64);
    float ba = __shfl(aggv, i0 + 1, 64);
    float a = (lane < 32) ? ax : aa;
    float b = (lane < 32) ? bx : ba;
    combin32[(size_t)wid * 64 + lane] = (unsigned)f2bf(a) | ((unsigned)f2bf(b) << 16);
}

// MFMA GEMM1: z[N][64] = combin[N][128] @ Wzt^T + bc. Block 64 rows, 4 waves.
// Fused: per-channel sum/sumsq of z accumulated into sums[0..64)/[64..128).
__global__ __launch_bounds__(256) void k_z(
    const unsigned short* __restrict__ combin, const unsigned short* __restrict__ Wzt,
    const float* __restrict__ bc, float* __restrict__ z, float* __restrict__ sums, int N) {
    __shared__ unsigned short a_lds[64 * 128];
    __shared__ unsigned short b_lds[64 * 128];
    __shared__ float redS[64], redQ[64];
    int t = threadIdx.x;
    int row0 = blockIdx.x * 64;
    for (int i = t; i < 1024; i += 256) {
        int row = i >> 4, seg = i & 15;
        int dsts = (row * 256 + ((seg * 16) ^ ((row & 7) << 4))) >> 1;
        int gr = row0 + row;
        s16x8 v = (s16x8)0;
        if (gr < N) v = *(const s16x8*)(combin + (size_t)gr * 128 + seg * 8);
        *(s16x8*)(a_lds + dsts) = v;
        *(s16x8*)(b_lds + dsts) = *(const s16x8*)(Wzt + (size_t)row * 128 + seg * 8);
    }
    if (t < 64) { redS[t] = 0.f; redQ[t] = 0.f; }
    __syncthreads();
    int w = t >> 6, l = t & 63, hi = l >> 4, lo = l & 15;
    int ar = w * 16 + lo;
    s16x8 a[4];
#pragma unroll
    for (int kk = 0; kk < 4; ++kk) {
        int byte = (kk * 64 + hi * 16) ^ ((ar & 7) << 4);
        a[kk] = *(const s16x8*)(a_lds + ((ar * 256 + byte) >> 1));
    }
#pragma unroll
    for (int cf = 0; cf < 4; ++cf) {
        int br = cf * 16 + lo;
        f32x4 acc = (f32x4){0.f, 0.f, 0.f, 0.f};
#pragma unroll
        for (int kk = 0; kk < 4; ++kk) {
            int byte = (kk * 64 + hi * 16) ^ ((br & 7) << 4);
            s16x8 b = *(const s16x8*)(b_lds + ((br * 256 + byte) >> 1));
            acc = __builtin_amdgcn_mfma_f32_16x16x32_bf16(a[kk], b, acc, 0, 0, 0);
        }
        int colg = cf * 16 + lo;
        float bcv = bc[colg];
        float sv = 0.f, qv = 0.f;
#pragma unroll
        for (int r = 0; r < 4; ++r) {
            int rowg = row0 + w * 16 + hi * 4 + r;
            if (rowg < N) {
                float v = acc[r] + bcv;
                z[(size_t)rowg * 64 + colg] = v;
                sv += v; qv += v * v;
            }
        }
        atomicAdd(&redS[colg], sv);
        atomicAdd(&redQ[colg], qv);
    }
    __syncthreads();
    if (t < 64) {
        atomicAdd(&sums[t], redS[t]);
        atomicAdd(&sums[64 + t], redQ[t]);
    }
}

// Per-channel sum & sumsq for bf16 gout, C=512. uint4 loads; LDS reduce.
__global__ __launch_bounds__(256) void k_statsg(const u32x4* __restrict__ X,
                                                float* __restrict__ sums, int N) {
    __shared__ float redS[512], redQ[512];
    int t = threadIdx.x;
    for (int i = t; i < 512; i += 256) { redS[i] = 0.f; redQ[i] = 0.f; }
    __syncthreads();
    int qu = t & 63;
    int slice = (blockIdx.x << 2) | (t >> 6);
    int nsl = gridDim.x << 2;
    float s[8], q[8];
#pragma unroll
    for (int j = 0; j < 8; ++j) { s[j] = 0.f; q[j] = 0.f; }
    for (int n = slice; n < N; n += nsl) {
        u32x4 u = X[(size_t)n * 64 + qu];
        unsigned uu[4] = {u.x, u.y, u.z, u.w};
#pragma unroll
        for (int k2 = 0; k2 < 4; ++k2) {
            float a = bf_lo(uu[k2]), b = bf_hi(uu[k2]);
            s[2 * k2] += a; q[2 * k2] += a * a;
            s[2 * k2 + 1] += b; q[2 * k2 + 1] += b * b;
        }
    }
#pragma unroll
    for (int j = 0; j < 8; ++j) {
        atomicAdd(&redS[qu * 8 + j], s[j]);
        atomicAdd(&redQ[qu * 8 + j], q[j]);
    }
    __syncthreads();
    for (int i = t; i < 512; i += 256) {
        atomicAdd(&sums[i], redS[i]);
        atomicAdd(&sums[512 + i], redQ[i]);
    }
}

// MFMA GEMM2: xlr[N][1024] = [relu(bn(z)) | agg] @ Wt^T (bf16 out).
// BN of z applied inline during A-staging (sc/sh from zsums); agg half
// copied from combin. 64 rows x 256 cols per block.
__global__ __launch_bounds__(256) void k_xlxr2(
    const float* __restrict__ z, const unsigned short* __restrict__ combin,
    const unsigned short* __restrict__ Wt, const float* __restrict__ zsums,
    const float* __restrict__ g, const float* __restrict__ be,
    unsigned short* __restrict__ xlr, int N) {
    __shared__ unsigned short a_lds[64 * 128];
    __shared__ unsigned short b_lds[256 * 128];
    __shared__ float sc_l[64], sh_l[64];
    int t = threadIdx.x;
    int row0 = blockIdx.x * 64;
    int c0 = blockIdx.y * 256;
    float invN = 1.0f / (float)N;
    if (t < 64) {
        float mean = zsums[t] * invN;
        float var = zsums[64 + t] * invN - mean * mean;
        float s = g[t] * rsqrtf(var + 1e-5f);
        sc_l[t] = s;
        sh_l[t] = be[t] - mean * s;
    }
    __syncthreads();
    for (int i = t; i < 1024; i += 256) {
        int row = i >> 4, seg = i & 15;
        int dsts = (row * 256 + ((seg * 16) ^ ((row & 7) << 4))) >> 1;
        int gr = row0 + row;
        s16x8 v = (s16x8)0;
        if (gr < N) {
            if (seg < 8) {                     // bf16(relu(bn(z))) channels
                int k0 = seg * 8;
                float4 z0 = *(const float4*)(z + (size_t)gr * 64 + k0);
                float4 z1 = *(const float4*)(z + (size_t)gr * 64 + k0 + 4);
                float zz[8] = {z0.x, z0.y, z0.z, z0.w, z1.x, z1.y, z1.z, z1.w};
#pragma unroll
                for (int j = 0; j < 8; ++j) {
                    float y = fmaxf(fmaf(zz[j], sc_l[k0 + j], sh_l[k0 + j]), 0.f);
                    v[j] = (short)f2bf(y);
                }
            } else {                           // agg half, already bf16
                v = *(const s16x8*)(combin + (size_t)gr * 128 + seg * 8);
            }
        }
        *(s16x8*)(a_lds + dsts) = v;
    }
    for (int i = t; i < 4096; i += 256) {
        int row = i >> 4, seg = i & 15;
        int dsts = (row * 256 + ((seg * 16) ^ ((row & 7) << 4))) >> 1;
        *(s16x8*)(b_lds + dsts) = *(const s16x8*)(Wt + (size_t)(c0 + row) * 128 + seg * 8);
    }
    __syncthreads();
    int w = t >> 6, l = t & 63, hi = l >> 4, lo = l & 15;
    int ar = w * 16 + lo;
    s16x8 a[4];
#pragma unroll
    for (int kk = 0; kk < 4; ++kk) {
        int byte = (kk * 64 + hi * 16) ^ ((ar & 7) << 4);
        a[kk] = *(const s16x8*)(a_lds + ((ar * 256 + byte) >> 1));
    }
#pragma unroll
    for (int cf = 0; cf < 16; ++cf) {
        int br = cf * 16 + lo;
        f32x4 acc = (f32x4){0.f, 0.f, 0.f, 0.f};
#pragma unroll
        for (int kk = 0; kk < 4; ++kk) {
            int byte = (kk * 64 + hi * 16) ^ ((br & 7) << 4);
            s16x8 b = *(const s16x8*)(b_lds + ((br * 256 + byte) >> 1));
            acc = __builtin_amdgcn_mfma_f32_16x16x32_bf16(a[kk], b, acc, 0, 0, 0);
        }
        int colg = c0 + cf * 16 + lo;
#pragma unroll
        for (int r = 0; r < 4; ++r) {
            int rowg = row0 + w * 16 + hi * 4 + r;
            if (rowg < N) xlr[(size_t)rowg * 1024 + colg] = f2bf(acc[r]);
        }
    }
}

// Per-edge softmax weight + aggregation for one edge (helper).
__device__ inline void gat_edge(u32x4 u, const float* xrv, const float* av,
                                float* acc, float& s) {
    float xlv[8];
    unp8(u, xlv);
    float ps = 0.f;
#pragma unroll
    for (int j = 0; j < 8; ++j) {
        float t = xlv[j] + xrv[j];
        t = fmaxf(t, 0.2f * t);              // leaky_relu(t, 0.2)
        ps = fmaf(t, av[j], ps);
    }
    ps += __shfl_xor(ps, 1, 64);
    ps += __shfl_xor(ps, 2, 64);
    ps += __shfl_xor(ps, 4, 64);             // per-head score in 8-lane groups
    float w = __expf(ps);
    s += w;
#pragma unroll
    for (int j = 0; j < 8; ++j) acc[j] = fmaf(w, xlv[j], acc[j]);
}

// GATv2 per-dst softmax (no max subtraction: |score| <~ 3 here; softmax is
// shift-invariant) + weighted aggregation. One wave per dst node. Edge
// indices preloaded 64-at-a-time with one coalesced load + shfl broadcast;
// 4x unrolled gathers.
__global__ __launch_bounds__(256) void k_gat(
    const unsigned short* __restrict__ xlr, unsigned* __restrict__ gout32,
    const int* __restrict__ rowptr, const int* __restrict__ esrc,
    const float* __restrict__ att, const float* __restrict__ bg, int N) {
    int wid = (blockIdx.x * blockDim.x + threadIdx.x) >> 6;
    int lane = threadIdx.x & 63;
    if (wid >= N) return;
    int n = wid;
    float xrv[8], av[8], acc[8];
    {
        u32x4 u = *(const u32x4*)(xlr + (size_t)n * 1024 + 512 + lane * 8);
        unp8(u, xrv);
    }
    {
        float4 a0 = *(const float4*)(att + lane * 8);
        float4 a1 = *(const float4*)(att + lane * 8 + 4);
        av[0] = a0.x; av[1] = a0.y; av[2] = a0.z; av[3] = a0.w;
        av[4] = a1.x; av[5] = a1.y; av[6] = a1.z; av[7] = a1.w;
    }
#pragma unroll
    for (int j = 0; j < 8; ++j) acc[j] = 0.f;
    float s = 0.f;
    int e0 = rowptr[n], e1 = rowptr[n + 1];
    int m = e1 - e0 + 1;                     // real edges + self loop
    for (int base = 0; base < m; base += 64) {
        int ie = e0 + base + lane;
        int myIdx = (ie < e1) ? esrc[ie] : n;   // coalesced; ==n for self/tail
        int cnt = min(64, m - base);
        int i = 0;
        for (; i + 4 <= cnt; i += 4) {
            int s0 = __shfl(myIdx, i, 64);
            int s1 = __shfl(myIdx, i + 1, 64);
            int s2 = __shfl(myIdx, i + 2, 64);
            int s3 = __shfl(myIdx, i + 3, 64);
            u32x4 u0 = *(const u32x4*)(xlr + (size_t)s0 * 1024 + lane * 8);
            u32x4 u1 = *(const u32x4*)(xlr + (size_t)s1 * 1024 + lane * 8);
            u32x4 u2 = *(const u32x4*)(xlr + (size_t)s2 * 1024 + lane * 8);
            u32x4 u3 = *(const u32x4*)(xlr + (size_t)s3 * 1024 + lane * 8);
            gat_edge(u0, xrv, av, acc, s);
            gat_edge(u1, xrv, av, acc, s);
            gat_edge(u2, xrv, av, acc, s);
            gat_edge(u3, xrv, av, acc, s);
        }
        for (; i + 2 <= cnt; i += 2) {
            int s0 = __shfl(myIdx, i, 64);
            int s1 = __shfl(myIdx, i + 1, 64);
            u32x4 u0 = *(const u32x4*)(xlr + (size_t)s0 * 1024 + lane * 8);
            u32x4 u1 = *(const u32x4*)(xlr + (size_t)s1 * 1024 + lane * 8);
            gat_edge(u0, xrv, av, acc, s);
            gat_edge(u1, xrv, av, acc, s);
        }
        if (i < cnt) {
            int s0 = __shfl(myIdx, i, 64);
            u32x4 u0 = *(const u32x4*)(xlr + (size_t)s0 * 1024 + lane * 8);
            gat_edge(u0, xrv, av, acc, s);
        }
    }
    float invs = 1.0f / s;
    float bgv[8];
    {
        float4 b0 = *(const float4*)(bg + lane * 8);
        float4 b1 = *(const float4*)(bg + lane * 8 + 4);
        bgv[0] = b0.x; bgv[1] = b0.y; bgv[2] = b0.z; bgv[3] = b0.w;
        bgv[4] = b1.x; bgv[5] = b1.y; bgv[6] = b1.z; bgv[7] = b1.w;
    }
    u32x4 o;
    o.x = (unsigned)f2bf(acc[0] * invs + bgv[0]) | ((unsigned)f2bf(acc[1] * invs + bgv[1]) << 16);
    o.y = (unsigned)f2bf(acc[2] * invs + bgv[2]) | ((unsigned)f2bf(acc[3] * invs + bgv[3]) << 16);
    o.z = (unsigned)f2bf(acc[4] * invs + bgv[4]) | ((unsigned)f2bf(acc[5] * invs + bgv[5]) << 16);
    o.w = (unsigned)f2bf(acc[6] * invs + bgv[6]) | ((unsigned)f2bf(acc[7] * invs + bgv[7]) << 16);
    *(u32x4*)(gout32 + (size_t)n * 256 + lane * 4) = o;
}

// MFMA post-GEMM: h1[N][64] = relu(bn(gout)) @ W_p1 + b_p1. BN params computed
// in-kernel from gsums into LDS. Fused h1 sum/sumsq into sums[0..128).
__global__ __launch_bounds__(256) void k_postm(
    const unsigned* __restrict__ gout32, const unsigned short* __restrict__ Wp1t,
    const float* __restrict__ gsums, const float* __restrict__ g,
    const float* __restrict__ be, const float* __restrict__ bp1,
    float* __restrict__ h1, float* __restrict__ sums, int N) {
    __shared__ unsigned short a_lds[64 * 128];
    __shared__ unsigned short b_lds[64 * 128];
    __shared__ float sc_l[512], sh_l[512];
    __shared__ float redS[64], redQ[64];
    int t = threadIdx.x;
    float invN = 1.0f / (float)N;
    for (int i = t; i < 512; i += 256) {
        float mean = gsums[i] * invN;
        float var = gsums[512 + i] * invN - mean * mean;
        float s = g[i] * rsqrtf(var + 1e-5f);
        sc_l[i] = s;
        sh_l[i] = be[i] - mean * s;
    }
    if (t < 64) { redS[t] = 0.f; redQ[t] = 0.f; }
    int row0 = blockIdx.x * 64;
    int w = t >> 6, l = t & 63, hi = l >> 4, lo = l & 15;
    int ar = w * 16 + lo;
    f32x4 acc[4];
#pragma unroll
    for (int cf = 0; cf < 4; ++cf) acc[cf] = (f32x4){0.f, 0.f, 0.f, 0.f};
    for (int kc = 0; kc < 4; ++kc) {
        __syncthreads();
        for (int i = t; i < 1024; i += 256) {
            int row = i >> 4, seg = i & 15;
            int dsts = (row * 256 + ((seg * 16) ^ ((row & 7) << 4))) >> 1;
            int gr = row0 + row;
            int k0 = kc * 128 + seg * 8;
            s16x8 v = (s16x8)0;
            if (gr < N) {
                u32x4 u = *(const u32x4*)(gout32 + (size_t)gr * 256 + (k0 >> 1));
                float f[8];
                unp8(u, f);
#pragma unroll
                for (int j = 0; j < 8; ++j) {
                    float y = fmaxf(fmaf(f[j], sc_l[k0 + j], sh_l[k0 + j]), 0.f);
                    v[j] = (short)f2bf(y);
                }
            }
            *(s16x8*)(a_lds + dsts) = v;
            *(s16x8*)(b_lds + dsts) = *(const s16x8*)(Wp1t + (size_t)row * 512 + k0);
        }
        __syncthreads();
        s16x8 a[4];
#pragma unroll
        for (int kk = 0; kk < 4; ++kk) {
            int byte = (kk * 64 + hi * 16) ^ ((ar & 7) << 4);
            a[kk] = *(const s16x8*)(a_lds + ((ar * 256 + byte) >> 1));
        }
#pragma unroll
        for (int cf = 0; cf < 4; ++cf) {
            int br = cf * 16 + lo;
#pragma unroll
            for (int kk = 0; kk < 4; ++kk) {
                int byte = (kk * 64 + hi * 16) ^ ((br & 7) << 4);
                s16x8 b = *(const s16x8*)(b_lds + ((br * 256 + byte) >> 1));
                acc[cf] = __builtin_amdgcn_mfma_f32_16x16x32_bf16(a[kk], b, acc[cf], 0, 0, 0);
            }
        }
    }
#pragma unroll
    for (int cf = 0; cf < 4; ++cf) {
        int colg = cf * 16 + lo;
        float bv = bp1[colg];
        float sv = 0.f, qv = 0.f;
#pragma unroll
        for (int r = 0; r < 4; ++r) {
            int rowg = row0 + w * 16 + hi * 4 + r;
            if (rowg < N) {
                float v = acc[cf][r] + bv;
                h1[(size_t)rowg * 64 + colg] = v;
                sv += v; qv += v * v;
            }
        }
        atomicAdd(&redS[colg], sv);
        atomicAdd(&redQ[colg], qv);
    }
    __syncthreads();
    if (t < 64) {
        atomicAdd(&sums[t], redS[t]);
        atomicAdd(&sums[64 + t], redQ[t]);
    }
}

// out[n] = relu(bn(h1 row)) . W_p2 + b_p2.  One wave per node.
__global__ void k_final(const float* __restrict__ h1, const float* __restrict__ stats,
                        const float* __restrict__ g, const float* __restrict__ be,
                        const float* __restrict__ Wp2, const float* __restrict__ bp2,
                        float* __restrict__ out, int N) {
    int wid = (blockIdx.x * blockDim.x + threadIdx.x) >> 6;
    int lane = threadIdx.x & 63;
    if (wid >= N) return;
    float invN = 1.0f / (float)N;
    float mean = stats[lane] * invN;
    float var = stats[64 + lane] * invN - mean * mean;
    float inv = rsqrtf(var + 1e-5f);
    float v = h1[(size_t)wid * 64 + lane];
    v = fmaxf((v - mean) * (inv * g[lane]) + be[lane], 0.f);
    float p = v * Wp2[lane];
#pragma unroll
    for (int off = 32; off; off >>= 1) p += __shfl_xor(p, off, 64);
    if (lane == 0) out[wid] = p + bp2[0];
}

extern "C" void kernel_launch(void* const* d_in, const int* in_sizes, int n_in,
                              void* d_out, int out_size, void* d_ws, size_t ws_size,
                              hipStream_t stream) {
    const float* x      = (const float*)d_in[0];
    const int*   ei     = (const int*)d_in[1];
    const float* ea     = (const float*)d_in[2];
    const float* W_ap   = (const float*)d_in[3];
    const float* b_ap   = (const float*)d_in[4];
    const float* W_ep   = (const float*)d_in[5];
    const float* b_ep   = (const float*)d_in[6];
    const float* W_msg  = (const float*)d_in[7];
    const float* b_msg  = (const float*)d_in[8];
    const float* g_msg  = (const float*)d_in[9];
    const float* be_msg = (const float*)d_in[10];
    const float* W_l    = (const float*)d_in[11];
    const float* W_r    = (const float*)d_in[12];
    const float* att    = (const float*)d_in[13];
    const float* b_gat  = (const float*)d_in[14];
    const float* g_bn   = (const float*)d_in[15];
    const float* be_bn  = (const float*)d_in[16];
    const float* W_p1   = (const float*)d_in[17];
    const float* b_p1   = (const float*)d_in[18];
    const float* g_p    = (const float*)d_in[19];
    const float* be_p   = (const float*)d_in[20];
    const float* W_p2   = (const float*)d_in[21];
    const float* b_p2   = (const float*)d_in[22];

    int N = in_sizes[0] / 64;
    int E = in_sizes[1] / 2;
    int nb = CDIV(N, 1024);

    // Workspace layout (floats). Zeroed prefix first.
    float* ws = (float*)d_ws;
    size_t off = 0;
    int*   cntI   = (int*)(ws + off); off += N;
    int*   cursor = (int*)(ws + off); off += N;
    float* st_msg = ws + off; off += 128;
    float* st_gat = ws + off; off += 1024;
    float* st_p   = ws + off; off += 128;
    size_t zero_floats = off;
    unsigned short* combin = (unsigned short*)(ws + off); off += (size_t)N * 64;  // N*128 bf16
    float* zb     = ws + off; off += (size_t)N * 64;       // z, later reused as h1
    unsigned short* Wzt = (unsigned short*)(ws + off); off += 4096;               // 64*128 bf16 = 4096 floats
    float* bc     = ws + off; off += 64;
    int*   rowptr = (int*)(ws + off); off += (size_t)(N + 1); off = (off + 3) & ~(size_t)3;
    int*   esrc   = (int*)(ws + off); off += E;
    int*   eidx   = (int*)(ws + off); off += E;
    int*   bsum   = (int*)(ws + off); off += 64;
    int*   boff   = (int*)(ws + off); off += 64;
    unsigned short* Wt  = (unsigned short*)(ws + off); off += 65536;              // 1024*128 bf16
    unsigned short* Wp1t = (unsigned short*)(ws + off); off += 16384;             // 64*512 bf16
    unsigned short* xlr = (unsigned short*)(ws + off); off += (size_t)N * 512;    // N*1024 bf16
    unsigned* gout32 = (unsigned*)(ws + off); off += (size_t)N * 256;             // N*512 bf16
    float* h1 = zb;

    hipMemsetAsync(d_ws, 0, zero_floats * sizeof(float), stream);

    k_prepcnt<<<641 + CDIV(E, 256), 256, 0, stream>>>(
        W_l, W_r, W_p1, W_ap, W_msg, b_ap, b_msg, Wt, Wp1t, Wzt, bc, ei, cntI, E);
    k_bsum<<<nb, 256, 0, stream>>>(cntI, bsum, N);
    k_boff<<<1, 64, 0, stream>>>(bsum, boff, nb);
    k_scan2<<<nb, 256, 0, stream>>>(cntI, boff, rowptr, N);
    k_fill<<<CDIV(E, 256), 256, 0, stream>>>(ei, rowptr, cursor, esrc, eidx, E);
    k_combin<<<CDIV(N * 64, 256), 256, 0, stream>>>(x, ea, rowptr, eidx, W_ep, b_ep,
                                                    (unsigned*)combin, N);
    k_z<<<CDIV(N, 64), 256, 0, stream>>>(combin, Wzt, bc, zb, st_msg, N);
    dim3 gx(CDIV(N, 64), 4);
    k_xlxr2<<<gx, 256, 0, stream>>>(zb, combin, Wt, st_msg, g_msg, be_msg, xlr, N);
    k_gat<<<CDIV(N * 64, 256), 256, 0, stream>>>(xlr, gout32, rowptr, esrc, att, b_gat, N);
    k_statsg<<<256, 256, 0, stream>>>((const u32x4*)gout32, st_gat, N);
    k_postm<<<CDIV(N, 64), 256, 0, stream>>>(gout32, Wp1t, st_gat, g_bn, be_bn,
                                             b_p1, h1, st_p, N);
    k_final<<<CDIV(N * 64, 256), 256, 0, stream>>>(h1, st_p, g_p, be_p, W_p2, b_p2,
                                                   (float*)d_out, N);
}

// Round 14
// 379.407 us; speedup vs baseline: 1.0945x; 1.0945x over previous
//
#include <hip/hip_runtime.h>
#include <hip/hip_bf16.h>

// ---------------------------------------------------------------------------
// GATv2 model pipeline. N=50000, E=400000, HID=64, H=8.
// Round 14: fix round-13 occupancy cliff — the 512B sc_l/sh_l LDS arrays
// pushed k_xlxr2 from exactly 80KB (2 blocks/CU) to 80.5KB (1 block/CU).
// BN params now precomputed by a tiny kernel and read from global (cached).
// ---------------------------------------------------------------------------

#define CDIV(a, b) (((a) + (b) - 1) / (b))

using f32x4 = __attribute__((ext_vector_type(4))) float;
using s16x8 = __attribute__((ext_vector_type(8))) short;
using u32x4 = __attribute__((ext_vector_type(4))) unsigned;

__device__ inline unsigned short f2bf(float f) {
    union { float f; unsigned u; } v; v.f = f;
    unsigned r = v.u + 0x7fff + ((v.u >> 16) & 1);   // round-nearest-even
    return (unsigned short)(r >> 16);
}
__device__ inline float bf_lo(unsigned w) {
    union { unsigned u; float f; } v; v.u = w << 16; return v.f;
}
__device__ inline float bf_hi(unsigned w) {
    union { unsigned u; float f; } v; v.u = w & 0xffff0000u; return v.f;
}
__device__ inline void unp8(u32x4 u, float* v) {
    v[0] = bf_lo(u.x); v[1] = bf_hi(u.x); v[2] = bf_lo(u.y); v[3] = bf_hi(u.y);
    v[4] = bf_lo(u.z); v[5] = bf_hi(u.z); v[6] = bf_lo(u.w); v[7] = bf_hi(u.w);
}

// Merged: blocks [0,512) -> Wt; [512,640) -> Wp1t; 640 -> Wzt+bc;
// blocks >= 641 -> in-degree count (1 atomic per edge, 50000 targets).
__global__ void k_prepcnt(const float* __restrict__ Wl, const float* __restrict__ Wr,
                          const float* __restrict__ Wp1, const float* __restrict__ Wap,
                          const float* __restrict__ Wmsg, const float* __restrict__ bap,
                          const float* __restrict__ bmsg, unsigned short* __restrict__ Wt,
                          unsigned short* __restrict__ Wp1t, unsigned short* __restrict__ Wzt,
                          float* __restrict__ bc, const int* __restrict__ ei,
                          int* __restrict__ cntI, int E) {
    int b = blockIdx.x, t = threadIdx.x;
    if (b < 512) {                       // Wt[c][k], [1024][128]
        int idx = b * 256 + t;
        int c = idx >> 7, k = idx & 127;
        float v = (c < 512) ? Wl[(size_t)k * 512 + c] : Wr[(size_t)k * 512 + (c - 512)];
        Wt[idx] = f2bf(v);
    } else if (b < 640) {                // Wp1t[c][k], [64][512]
        int idx = (b - 512) * 256 + t;
        int c = idx >> 9, k = idx & 511;
        Wp1t[idx] = f2bf(Wp1[(size_t)k * 64 + c]);
    } else if (b == 640) {               // Wzt + bc (single block)
        for (int e = t; e < 4096; e += 256) {
            int i = e >> 6, c = e & 63;
            float s = 0.f;
            for (int j = 0; j < 64; ++j) s += Wap[i * 64 + j] * Wmsg[j * 64 + c];
            Wzt[c * 128 + i] = f2bf(s);
        }
        for (int e = t; e < 4096; e += 256) {
            int k = e >> 6, c = e & 63;
            Wzt[c * 128 + 64 + k] = f2bf(Wmsg[k * 64 + c]);
        }
        if (t < 64) {
            float s = bmsg[t];
            for (int j = 0; j < 64; ++j) s += bap[j] * Wmsg[j * 64 + t];
            bc[t] = s;
        }
    } else {                             // degree count
        int e = (b - 641) * 256 + t;
        if (e < E) atomicAdd(&cntI[ei[E + e]], 1);
    }
}

// ---- parallel exclusive scan of cntI -> rowptr (3 kernels) ----
__global__ void k_bsum(const int* __restrict__ cntI, int* __restrict__ bsum, int N) {
    int b = blockIdx.x, t = threadIdx.x;
    int base = b * 1024 + t * 4;
    int s = 0;
#pragma unroll
    for (int j = 0; j < 4; ++j) { int i = base + j; if (i < N) s += cntI[i]; }
    for (int off = 32; off; off >>= 1) s += __shfl_xor(s, off, 64);
    __shared__ int wsum[4];
    if ((t & 63) == 0) wsum[t >> 6] = s;
    __syncthreads();
    if (t == 0) bsum[b] = wsum[0] + wsum[1] + wsum[2] + wsum[3];
}
__global__ void k_boff(const int* __restrict__ bsum, int* __restrict__ boff, int nb) {
    int t = threadIdx.x;
    if (t < nb) { int s = 0; for (int j = 0; j < t; ++j) s += bsum[j]; boff[t] = s; }
}
__global__ void k_scan2(const int* __restrict__ cntI, const int* __restrict__ boff,
                        int* __restrict__ rowptr, int N) {
    int b = blockIdx.x, t = threadIdx.x;
    int base = b * 1024 + t * 4;
    int v[4]; int s = 0;
#pragma unroll
    for (int j = 0; j < 4; ++j) { int i = base + j; v[j] = (i < N) ? cntI[i] : 0; s += v[j]; }
    __shared__ int ls[256];
    ls[t] = s; __syncthreads();
    for (int off = 1; off < 256; off <<= 1) {
        int tv = (t >= (int)off) ? ls[t - off] : 0;
        __syncthreads(); ls[t] += tv; __syncthreads();
    }
    int run = ls[t] - s + boff[b];
#pragma unroll
    for (int j = 0; j < 4; ++j) { run += v[j]; int i = base + j; if (i < N) rowptr[i + 1] = run; }
    if (b == 0 && t == 0) rowptr[0] = 0;
}

// Scatter edges into CSR order: store source node AND edge id.
__global__ void k_fill(const int* __restrict__ ei, const int* __restrict__ rowptr,
                       int* __restrict__ cursor, int* __restrict__ esrc,
                       int* __restrict__ eidx, int E) {
    int e = blockIdx.x * blockDim.x + threadIdx.x;
    if (e >= E) return;
    int dst = ei[E + e];
    int pos = rowptr[dst] + atomicAdd(&cursor[dst], 1);
    esrc[pos] = ei[e];
    eidx[pos] = e;
}

// One wave per node: agg = deg>0 ? mean_{in-edges}(edge_attr)@W_ep + b_ep : 0
// (gathered via CSR, 4 edges x 16 ch per iteration, no atomics), then
// combin row = [bf16(x) | bf16(agg)] with wave-uniform shuffles.
__global__ void k_combin(const float* __restrict__ x, const float* __restrict__ ea,
                         const int* __restrict__ rowptr, const int* __restrict__ eidx,
                         const float* __restrict__ Wep, const float* __restrict__ bep,
                         unsigned* __restrict__ combin32, int N) {
    int wid = (blockIdx.x * blockDim.x + threadIdx.x) >> 6;
    int lane = threadIdx.x & 63;
    if (wid >= N) return;
    int e0 = rowptr[wid], e1 = rowptr[wid + 1];
    int deg = e1 - e0;
    int le = lane >> 4, ch = lane & 15;
    float part = 0.f;
    for (int p = e0 + le; p < e1; p += 4)
        part += ea[(size_t)eidx[p] * 16 + ch];
    part += __shfl_xor(part, 16, 64);
    part += __shfl_xor(part, 32, 64);          // full sum for channel ch
    float mval = (deg > 0) ? part / (float)deg : 0.f;
    float aggv = bep[lane];
#pragma unroll
    for (int j = 0; j < 16; ++j) {
        float mj = __shfl(mval, j, 64);        // lane j holds channel j
        aggv = fmaf(mj, Wep[j * 64 + lane], aggv);
    }
    if (deg == 0) aggv = 0.f;
    float xv = x[(size_t)wid * 64 + lane];
    int i0 = (lane & 31) * 2;                  // uniform shuffles, select after
    float ax = __shfl(xv, i0, 64);
    float bx = __shfl(xv, i0 + 1, 64);
    float aa = __shfl(aggv, i0, 64);
    float ba = __shfl(aggv, i0 + 1, 64);
    float a = (lane < 32) ? ax : aa;
    float b = (lane < 32) ? bx : ba;
    combin32[(size_t)wid * 64 + lane] = (unsigned)f2bf(a) | ((unsigned)f2bf(b) << 16);
}

// MFMA GEMM1: z[N][64] = combin[N][128] @ Wzt^T + bc. Block 64 rows, 4 waves.
// Fused: per-channel sum/sumsq of z accumulated into sums[0..64)/[64..128).
__global__ __launch_bounds__(256) void k_z(
    const unsigned short* __restrict__ combin, const unsigned short* __restrict__ Wzt,
    const float* __restrict__ bc, float* __restrict__ z, float* __restrict__ sums, int N) {
    __shared__ unsigned short a_lds[64 * 128];
    __shared__ unsigned short b_lds[64 * 128];
    __shared__ float redS[64], redQ[64];
    int t = threadIdx.x;
    int row0 = blockIdx.x * 64;
    for (int i = t; i < 1024; i += 256) {
        int row = i >> 4, seg = i & 15;
        int dsts = (row * 256 + ((seg * 16) ^ ((row & 7) << 4))) >> 1;
        int gr = row0 + row;
        s16x8 v = (s16x8)0;
        if (gr < N) v = *(const s16x8*)(combin + (size_t)gr * 128 + seg * 8);
        *(s16x8*)(a_lds + dsts) = v;
        *(s16x8*)(b_lds + dsts) = *(const s16x8*)(Wzt + (size_t)row * 128 + seg * 8);
    }
    if (t < 64) { redS[t] = 0.f; redQ[t] = 0.f; }
    __syncthreads();
    int w = t >> 6, l = t & 63, hi = l >> 4, lo = l & 15;
    int ar = w * 16 + lo;
    s16x8 a[4];
#pragma unroll
    for (int kk = 0; kk < 4; ++kk) {
        int byte = (kk * 64 + hi * 16) ^ ((ar & 7) << 4);
        a[kk] = *(const s16x8*)(a_lds + ((ar * 256 + byte) >> 1));
    }
#pragma unroll
    for (int cf = 0; cf < 4; ++cf) {
        int br = cf * 16 + lo;
        f32x4 acc = (f32x4){0.f, 0.f, 0.f, 0.f};
#pragma unroll
        for (int kk = 0; kk < 4; ++kk) {
            int byte = (kk * 64 + hi * 16) ^ ((br & 7) << 4);
            s16x8 b = *(const s16x8*)(b_lds + ((br * 256 + byte) >> 1));
            acc = __builtin_amdgcn_mfma_f32_16x16x32_bf16(a[kk], b, acc, 0, 0, 0);
        }
        int colg = cf * 16 + lo;
        float bcv = bc[colg];
        float sv = 0.f, qv = 0.f;
#pragma unroll
        for (int r = 0; r < 4; ++r) {
            int rowg = row0 + w * 16 + hi * 4 + r;
            if (rowg < N) {
                float v = acc[r] + bcv;
                z[(size_t)rowg * 64 + colg] = v;
                sv += v; qv += v * v;
            }
        }
        atomicAdd(&redS[colg], sv);
        atomicAdd(&redQ[colg], qv);
    }
    __syncthreads();
    if (t < 64) {
        atomicAdd(&sums[t], redS[t]);
        atomicAdd(&sums[64 + t], redQ[t]);
    }
}

// sc[k] = g/sqrt(var+eps), sh[k] = be - mean*sc (generic C).
__global__ void k_bnparam(const float* __restrict__ sums, const float* __restrict__ g,
                          const float* __restrict__ be, float* __restrict__ sc,
                          float* __restrict__ sh, int N, int C) {
    int k = blockIdx.x * blockDim.x + threadIdx.x;
    if (k >= C) return;
    float invN = 1.0f / (float)N;
    float mean = sums[k] * invN;
    float var = sums[C + k] * invN - mean * mean;
    float s = g[k] * rsqrtf(var + 1e-5f);
    sc[k] = s;
    sh[k] = be[k] - mean * s;
}

// Per-channel sum & sumsq for bf16 gout, C=512. uint4 loads; LDS reduce.
__global__ __launch_bounds__(256) void k_statsg(const u32x4* __restrict__ X,
                                                float* __restrict__ sums, int N) {
    __shared__ float redS[512], redQ[512];
    int t = threadIdx.x;
    for (int i = t; i < 512; i += 256) { redS[i] = 0.f; redQ[i] = 0.f; }
    __syncthreads();
    int qu = t & 63;
    int slice = (blockIdx.x << 2) | (t >> 6);
    int nsl = gridDim.x << 2;
    float s[8], q[8];
#pragma unroll
    for (int j = 0; j < 8; ++j) { s[j] = 0.f; q[j] = 0.f; }
    for (int n = slice; n < N; n += nsl) {
        u32x4 u = X[(size_t)n * 64 + qu];
        unsigned uu[4] = {u.x, u.y, u.z, u.w};
#pragma unroll
        for (int k2 = 0; k2 < 4; ++k2) {
            float a = bf_lo(uu[k2]), b = bf_hi(uu[k2]);
            s[2 * k2] += a; q[2 * k2] += a * a;
            s[2 * k2 + 1] += b; q[2 * k2 + 1] += b * b;
        }
    }
#pragma unroll
    for (int j = 0; j < 8; ++j) {
        atomicAdd(&redS[qu * 8 + j], s[j]);
        atomicAdd(&redQ[qu * 8 + j], q[j]);
    }
    __syncthreads();
    for (int i = t; i < 512; i += 256) {
        atomicAdd(&sums[i], redS[i]);
        atomicAdd(&sums[512 + i], redQ[i]);
    }
}

// MFMA GEMM2: xlr[N][1024] = [relu(bn(z)) | agg] @ Wt^T (bf16 out).
// BN of z applied inline during A-staging using precomputed sc2/sh2 (global,
// cached — keeps LDS at exactly 80KB = 2 blocks/CU). 64 rows x 256 cols.
__global__ __launch_bounds__(256) void k_xlxr2(
    const float* __restrict__ z, const unsigned short* __restrict__ combin,
    const unsigned short* __restrict__ Wt, const float* __restrict__ sc2,
    const float* __restrict__ sh2, unsigned short* __restrict__ xlr, int N) {
    __shared__ unsigned short a_lds[64 * 128];
    __shared__ unsigned short b_lds[256 * 128];
    int t = threadIdx.x;
    int row0 = blockIdx.x * 64;
    int c0 = blockIdx.y * 256;
    for (int i = t; i < 1024; i += 256) {
        int row = i >> 4, seg = i & 15;
        int dsts = (row * 256 + ((seg * 16) ^ ((row & 7) << 4))) >> 1;
        int gr = row0 + row;
        s16x8 v = (s16x8)0;
        if (gr < N) {
            if (seg < 8) {                     // bf16(relu(bn(z))) channels
                int k0 = seg * 8;
                float4 z0 = *(const float4*)(z + (size_t)gr * 64 + k0);
                float4 z1 = *(const float4*)(z + (size_t)gr * 64 + k0 + 4);
                float4 s0 = *(const float4*)(sc2 + k0);
                float4 s1 = *(const float4*)(sc2 + k0 + 4);
                float4 h0 = *(const float4*)(sh2 + k0);
                float4 h1 = *(const float4*)(sh2 + k0 + 4);
                float zz[8] = {z0.x, z0.y, z0.z, z0.w, z1.x, z1.y, z1.z, z1.w};
                float ss[8] = {s0.x, s0.y, s0.z, s0.w, s1.x, s1.y, s1.z, s1.w};
                float hh[8] = {h0.x, h0.y, h0.z, h0.w, h1.x, h1.y, h1.z, h1.w};
#pragma unroll
                for (int j = 0; j < 8; ++j) {
                    float y = fmaxf(fmaf(zz[j], ss[j], hh[j]), 0.f);
                    v[j] = (short)f2bf(y);
                }
            } else {                           // agg half, already bf16
                v = *(const s16x8*)(combin + (size_t)gr * 128 + seg * 8);
            }
        }
        *(s16x8*)(a_lds + dsts) = v;
    }
    for (int i = t; i < 4096; i += 256) {
        int row = i >> 4, seg = i & 15;
        int dsts = (row * 256 + ((seg * 16) ^ ((row & 7) << 4))) >> 1;
        *(s16x8*)(b_lds + dsts) = *(const s16x8*)(Wt + (size_t)(c0 + row) * 128 + seg * 8);
    }
    __syncthreads();
    int w = t >> 6, l = t & 63, hi = l >> 4, lo = l & 15;
    int ar = w * 16 + lo;
    s16x8 a[4];
#pragma unroll
    for (int kk = 0; kk < 4; ++kk) {
        int byte = (kk * 64 + hi * 16) ^ ((ar & 7) << 4);
        a[kk] = *(const s16x8*)(a_lds + ((ar * 256 + byte) >> 1));
    }
#pragma unroll
    for (int cf = 0; cf < 16; ++cf) {
        int br = cf * 16 + lo;
        f32x4 acc = (f32x4){0.f, 0.f, 0.f, 0.f};
#pragma unroll
        for (int kk = 0; kk < 4; ++kk) {
            int byte = (kk * 64 + hi * 16) ^ ((br & 7) << 4);
            s16x8 b = *(const s16x8*)(b_lds + ((br * 256 + byte) >> 1));
            acc = __builtin_amdgcn_mfma_f32_16x16x32_bf16(a[kk], b, acc, 0, 0, 0);
        }
        int colg = c0 + cf * 16 + lo;
#pragma unroll
        for (int r = 0; r < 4; ++r) {
            int rowg = row0 + w * 16 + hi * 4 + r;
            if (rowg < N) xlr[(size_t)rowg * 1024 + colg] = f2bf(acc[r]);
        }
    }
}

// Per-edge softmax weight + aggregation for one edge (helper).
__device__ inline void gat_edge(u32x4 u, const float* xrv, const float* av,
                                float* acc, float& s) {
    float xlv[8];
    unp8(u, xlv);
    float ps = 0.f;
#pragma unroll
    for (int j = 0; j < 8; ++j) {
        float t = xlv[j] + xrv[j];
        t = fmaxf(t, 0.2f * t);              // leaky_relu(t, 0.2)
        ps = fmaf(t, av[j], ps);
    }
    ps += __shfl_xor(ps, 1, 64);
    ps += __shfl_xor(ps, 2, 64);
    ps += __shfl_xor(ps, 4, 64);             // per-head score in 8-lane groups
    float w = __expf(ps);
    s += w;
#pragma unroll
    for (int j = 0; j < 8; ++j) acc[j] = fmaf(w, xlv[j], acc[j]);
}

// GATv2 per-dst softmax (no max subtraction: |score| <~ 3 here; softmax is
// shift-invariant) + weighted aggregation. One wave per dst node. Edge
// indices preloaded 64-at-a-time with one coalesced load + shfl broadcast;
// 4x unrolled gathers.
__global__ __launch_bounds__(256) void k_gat(
    const unsigned short* __restrict__ xlr, unsigned* __restrict__ gout32,
    const int* __restrict__ rowptr, const int* __restrict__ esrc,
    const float* __restrict__ att, const float* __restrict__ bg, int N) {
    int wid = (blockIdx.x * blockDim.x + threadIdx.x) >> 6;
    int lane = threadIdx.x & 63;
    if (wid >= N) return;
    int n = wid;
    float xrv[8], av[8], acc[8];
    {
        u32x4 u = *(const u32x4*)(xlr + (size_t)n * 1024 + 512 + lane * 8);
        unp8(u, xrv);
    }
    {
        float4 a0 = *(const float4*)(att + lane * 8);
        float4 a1 = *(const float4*)(att + lane * 8 + 4);
        av[0] = a0.x; av[1] = a0.y; av[2] = a0.z; av[3] = a0.w;
        av[4] = a1.x; av[5] = a1.y; av[6] = a1.z; av[7] = a1.w;
    }
#pragma unroll
    for (int j = 0; j < 8; ++j) acc[j] = 0.f;
    float s = 0.f;
    int e0 = rowptr[n], e1 = rowptr[n + 1];
    int m = e1 - e0 + 1;                     // real edges + self loop
    for (int base = 0; base < m; base += 64) {
        int ie = e0 + base + lane;
        int myIdx = (ie < e1) ? esrc[ie] : n;   // coalesced; ==n for self/tail
        int cnt = min(64, m - base);
        int i = 0;
        for (; i + 4 <= cnt; i += 4) {
            int s0 = __shfl(myIdx, i, 64);
            int s1 = __shfl(myIdx, i + 1, 64);
            int s2 = __shfl(myIdx, i + 2, 64);
            int s3 = __shfl(myIdx, i + 3, 64);
            u32x4 u0 = *(const u32x4*)(xlr + (size_t)s0 * 1024 + lane * 8);
            u32x4 u1 = *(const u32x4*)(xlr + (size_t)s1 * 1024 + lane * 8);
            u32x4 u2 = *(const u32x4*)(xlr + (size_t)s2 * 1024 + lane * 8);
            u32x4 u3 = *(const u32x4*)(xlr + (size_t)s3 * 1024 + lane * 8);
            gat_edge(u0, xrv, av, acc, s);
            gat_edge(u1, xrv, av, acc, s);
            gat_edge(u2, xrv, av, acc, s);
            gat_edge(u3, xrv, av, acc, s);
        }
        for (; i + 2 <= cnt; i += 2) {
            int s0 = __shfl(myIdx, i, 64);
            int s1 = __shfl(myIdx, i + 1, 64);
            u32x4 u0 = *(const u32x4*)(xlr + (size_t)s0 * 1024 + lane * 8);
            u32x4 u1 = *(const u32x4*)(xlr + (size_t)s1 * 1024 + lane * 8);
            gat_edge(u0, xrv, av, acc, s);
            gat_edge(u1, xrv, av, acc, s);
        }
        if (i < cnt) {
            int s0 = __shfl(myIdx, i, 64);
            u32x4 u0 = *(const u32x4*)(xlr + (size_t)s0 * 1024 + lane * 8);
            gat_edge(u0, xrv, av, acc, s);
        }
    }
    float invs = 1.0f / s;
    float bgv[8];
    {
        float4 b0 = *(const float4*)(bg + lane * 8);
        float4 b1 = *(const float4*)(bg + lane * 8 + 4);
        bgv[0] = b0.x; bgv[1] = b0.y; bgv[2] = b0.z; bgv[3] = b0.w;
        bgv[4] = b1.x; bgv[5] = b1.y; bgv[6] = b1.z; bgv[7] = b1.w;
    }
    u32x4 o;
    o.x = (unsigned)f2bf(acc[0] * invs + bgv[0]) | ((unsigned)f2bf(acc[1] * invs + bgv[1]) << 16);
    o.y = (unsigned)f2bf(acc[2] * invs + bgv[2]) | ((unsigned)f2bf(acc[3] * invs + bgv[3]) << 16);
    o.z = (unsigned)f2bf(acc[4] * invs + bgv[4]) | ((unsigned)f2bf(acc[5] * invs + bgv[5]) << 16);
    o.w = (unsigned)f2bf(acc[6] * invs + bgv[6]) | ((unsigned)f2bf(acc[7] * invs + bgv[7]) << 16);
    *(u32x4*)(gout32 + (size_t)n * 256 + lane * 4) = o;
}

// MFMA post-GEMM: h1[N][64] = relu(bn(gout)) @ W_p1 + b_p1. BN params computed
// in-kernel from gsums into LDS. Fused h1 sum/sumsq into sums[0..128).
__global__ __launch_bounds__(256) void k_postm(
    const unsigned* __restrict__ gout32, const unsigned short* __restrict__ Wp1t,
    const float* __restrict__ gsums, const float* __restrict__ g,
    const float* __restrict__ be, const float* __restrict__ bp1,
    float* __restrict__ h1, float* __restrict__ sums, int N) {
    __shared__ unsigned short a_lds[64 * 128];
    __shared__ unsigned short b_lds[64 * 128];
    __shared__ float sc_l[512], sh_l[512];
    __shared__ float redS[64], redQ[64];
    int t = threadIdx.x;
    float invN = 1.0f / (float)N;
    for (int i = t; i < 512; i += 256) {
        float mean = gsums[i] * invN;
        float var = gsums[512 + i] * invN - mean * mean;
        float s = g[i] * rsqrtf(var + 1e-5f);
        sc_l[i] = s;
        sh_l[i] = be[i] - mean * s;
    }
    if (t < 64) { redS[t] = 0.f; redQ[t] = 0.f; }
    int row0 = blockIdx.x * 64;
    int w = t >> 6, l = t & 63, hi = l >> 4, lo = l & 15;
    int ar = w * 16 + lo;
    f32x4 acc[4];
#pragma unroll
    for (int cf = 0; cf < 4; ++cf) acc[cf] = (f32x4){0.f, 0.f, 0.f, 0.f};
    for (int kc = 0; kc < 4; ++kc) {
        __syncthreads();
        for (int i = t; i < 1024; i += 256) {
            int row = i >> 4, seg = i & 15;
            int dsts = (row * 256 + ((seg * 16) ^ ((row & 7) << 4))) >> 1;
            int gr = row0 + row;
            int k0 = kc * 128 + seg * 8;
            s16x8 v = (s16x8)0;
            if (gr < N) {
                u32x4 u = *(const u32x4*)(gout32 + (size_t)gr * 256 + (k0 >> 1));
                float f[8];
                unp8(u, f);
#pragma unroll
                for (int j = 0; j < 8; ++j) {
                    float y = fmaxf(fmaf(f[j], sc_l[k0 + j], sh_l[k0 + j]), 0.f);
                    v[j] = (short)f2bf(y);
                }
            }
            *(s16x8*)(a_lds + dsts) = v;
            *(s16x8*)(b_lds + dsts) = *(const s16x8*)(Wp1t + (size_t)row * 512 + k0);
        }
        __syncthreads();
        s16x8 a[4];
#pragma unroll
        for (int kk = 0; kk < 4; ++kk) {
            int byte = (kk * 64 + hi * 16) ^ ((ar & 7) << 4);
            a[kk] = *(const s16x8*)(a_lds + ((ar * 256 + byte) >> 1));
        }
#pragma unroll
        for (int cf = 0; cf < 4; ++cf) {
            int br = cf * 16 + lo;
#pragma unroll
            for (int kk = 0; kk < 4; ++kk) {
                int byte = (kk * 64 + hi * 16) ^ ((br & 7) << 4);
                s16x8 b = *(const s16x8*)(b_lds + ((br * 256 + byte) >> 1));
                acc[cf] = __builtin_amdgcn_mfma_f32_16x16x32_bf16(a[kk], b, acc[cf], 0, 0, 0);
            }
        }
    }
#pragma unroll
    for (int cf = 0; cf < 4; ++cf) {
        int colg = cf * 16 + lo;
        float bv = bp1[colg];
        float sv = 0.f, qv = 0.f;
#pragma unroll
        for (int r = 0; r < 4; ++r) {
            int rowg = row0 + w * 16 + hi * 4 + r;
            if (rowg < N) {
                float v = acc[cf][r] + bv;
                h1[(size_t)rowg * 64 + colg] = v;
                sv += v; qv += v * v;
            }
        }
        atomicAdd(&redS[colg], sv);
        atomicAdd(&redQ[colg], qv);
    }
    __syncthreads();
    if (t < 64) {
        atomicAdd(&sums[t], redS[t]);
        atomicAdd(&sums[64 + t], redQ[t]);
    }
}

// out[n] = relu(bn(h1 row)) . W_p2 + b_p2.  One wave per node.
__global__ void k_final(const float* __restrict__ h1, const float* __restrict__ stats,
                        const float* __restrict__ g, const float* __restrict__ be,
                        const float* __restrict__ Wp2, const float* __restrict__ bp2,
                        float* __restrict__ out, int N) {
    int wid = (blockIdx.x * blockDim.x + threadIdx.x) >> 6;
    int lane = threadIdx.x & 63;
    if (wid >= N) return;
    float invN = 1.0f / (float)N;
    float mean = stats[lane] * invN;
    float var = stats[64 + lane] * invN - mean * mean;
    float inv = rsqrtf(var + 1e-5f);
    float v = h1[(size_t)wid * 64 + lane];
    v = fmaxf((v - mean) * (inv * g[lane]) + be[lane], 0.f);
    float p = v * Wp2[lane];
#pragma unroll
    for (int off = 32; off; off >>= 1) p += __shfl_xor(p, off, 64);
    if (lane == 0) out[wid] = p + bp2[0];
}

extern "C" void kernel_launch(void* const* d_in, const int* in_sizes, int n_in,
                              void* d_out, int out_size, void* d_ws, size_t ws_size,
                              hipStream_t stream) {
    const float* x      = (const float*)d_in[0];
    const int*   ei     = (const int*)d_in[1];
    const float* ea     = (const float*)d_in[2];
    const float* W_ap   = (const float*)d_in[3];
    const float* b_ap   = (const float*)d_in[4];
    const float* W_ep   = (const float*)d_in[5];
    const float* b_ep   = (const float*)d_in[6];
    const float* W_msg  = (const float*)d_in[7];
    const float* b_msg  = (const float*)d_in[8];
    const float* g_msg  = (const float*)d_in[9];
    const float* be_msg = (const float*)d_in[10];
    const float* W_l    = (const float*)d_in[11];
    const float* W_r    = (const float*)d_in[12];
    const float* att    = (const float*)d_in[13];
    const float* b_gat  = (const float*)d_in[14];
    const float* g_bn   = (const float*)d_in[15];
    const float* be_bn  = (const float*)d_in[16];
    const float* W_p1   = (const float*)d_in[17];
    const float* b_p1   = (const float*)d_in[18];
    const float* g_p    = (const float*)d_in[19];
    const float* be_p   = (const float*)d_in[20];
    const float* W_p2   = (const float*)d_in[21];
    const float* b_p2   = (const float*)d_in[22];

    int N = in_sizes[0] / 64;
    int E = in_sizes[1] / 2;
    int nb = CDIV(N, 1024);

    // Workspace layout (floats). Zeroed prefix first.
    float* ws = (float*)d_ws;
    size_t off = 0;
    int*   cntI   = (int*)(ws + off); off += N;
    int*   cursor = (int*)(ws + off); off += N;
    float* st_msg = ws + off; off += 128;
    float* st_gat = ws + off; off += 1024;
    float* st_p   = ws + off; off += 128;
    size_t zero_floats = off;
    float* sc2    = ws + off; off += 64;
    float* sh2    = ws + off; off += 64;
    unsigned short* combin = (unsigned short*)(ws + off); off += (size_t)N * 64;  // N*128 bf16
    float* zb     = ws + off; off += (size_t)N * 64;       // z, later reused as h1
    unsigned short* Wzt = (unsigned short*)(ws + off); off += 4096;               // 64*128 bf16 = 4096 floats
    float* bc     = ws + off; off += 64;
    int*   rowptr = (int*)(ws + off); off += (size_t)(N + 1); off = (off + 3) & ~(size_t)3;
    int*   esrc   = (int*)(ws + off); off += E;
    int*   eidx   = (int*)(ws + off); off += E;
    int*   bsum   = (int*)(ws + off); off += 64;
    int*   boff   = (int*)(ws + off); off += 64;
    unsigned short* Wt  = (unsigned short*)(ws + off); off += 65536;              // 1024*128 bf16
    unsigned short* Wp1t = (unsigned short*)(ws + off); off += 16384;             // 64*512 bf16
    unsigned short* xlr = (unsigned short*)(ws + off); off += (size_t)N * 512;    // N*1024 bf16
    unsigned* gout32 = (unsigned*)(ws + off); off += (size_t)N * 256;             // N*512 bf16
    float* h1 = zb;

    hipMemsetAsync(d_ws, 0, zero_floats * sizeof(float), stream);

    k_prepcnt<<<641 + CDIV(E, 256), 256, 0, stream>>>(
        W_l, W_r, W_p1, W_ap, W_msg, b_ap, b_msg, Wt, Wp1t, Wzt, bc, ei, cntI, E);
    k_bsum<<<nb, 256, 0, stream>>>(cntI, bsum, N);
    k_boff<<<1, 64, 0, stream>>>(bsum, boff, nb);
    k_scan2<<<nb, 256, 0, stream>>>(cntI, boff, rowptr, N);
    k_fill<<<CDIV(E, 256), 256, 0, stream>>>(ei, rowptr, cursor, esrc, eidx, E);
    k_combin<<<CDIV(N * 64, 256), 256, 0, stream>>>(x, ea, rowptr, eidx, W_ep, b_ep,
                                                    (unsigned*)combin, N);
    k_z<<<CDIV(N, 64), 256, 0, stream>>>(combin, Wzt, bc, zb, st_msg, N);
    k_bnparam<<<1, 64, 0, stream>>>(st_msg, g_msg, be_msg, sc2, sh2, N, 64);
    dim3 gx(CDIV(N, 64), 4);
    k_xlxr2<<<gx, 256, 0, stream>>>(zb, combin, Wt, sc2, sh2, xlr, N);
    k_gat<<<CDIV(N * 64, 256), 256, 0, stream>>>(xlr, gout32, rowptr, esrc, att, b_gat, N);
    k_statsg<<<256, 256, 0, stream>>>((const u32x4*)gout32, st_gat, N);
    k_postm<<<CDIV(N, 64), 256, 0, stream>>>(gout32, Wp1t, st_gat, g_bn, be_bn,
                                             b_p1, h1, st_p, N);
    k_final<<<CDIV(N * 64, 256), 256, 0, stream>>>(h1, st_p, g_p, be_p, W_p2, b_p2,
                                                   (float*)d_out, N);
}